// Round 7
// baseline (255.807 us; speedup 1.0000x reference)
//
#include <hip/hip_runtime.h>
#include <hip/hip_bf16.h>
#include <cstdint>

#define SEQ 192

typedef float f32x4 __attribute__((ext_vector_type(4)));
typedef float f32x8 __attribute__((ext_vector_type(8)));
typedef __bf16 bf16;
typedef __bf16 bf16x8 __attribute__((ext_vector_type(8)));
typedef __bf16 bf16x4 __attribute__((ext_vector_type(4)));

#define MFMA_BF16(a, b, c) __builtin_amdgcn_mfma_f32_16x16x32_bf16(a, b, c, 0, 0, 0)

__device__ __forceinline__ bf16x8 cvt8(f32x8 v) {
  bf16x8 o;
#pragma unroll
  for (int i = 0; i < 8; i++) o[i] = (bf16)v[i];
  return o;
}

// =================== K1: WVt2 transpose + LayerNorm ===================
// WVt2[h][(f*64+g)*64 + h'] = WV[h][h'][g][f]  (so row-major t == consumer layout)
__global__ __launch_bounds__(256) void k1_prep(
    const float* __restrict__ x, const float* __restrict__ ln_w, const float* __restrict__ ln_b,
    const float* __restrict__ WV, bf16* __restrict__ xn_bf, bf16* __restrict__ WVt2) {
  int bid = blockIdx.x, tid = threadIdx.x;
  if (bid < 512) {
    int g = bid & 63, hh = bid >> 6;
    __shared__ float ld[64 * 65];
    int f = tid & 63, r4 = tid >> 6;
#pragma unroll
    for (int it = 0; it < 16; it++) {
      int hp = it * 4 + r4;
      ld[hp * 65 + f] = WV[(((size_t)(hh * 64 + hp) * 64 + g) * 64) + f];
    }
    __syncthreads();
    int hp2 = tid & 63;
#pragma unroll
    for (int it = 0; it < 16; it++) {
      int ff = it * 4 + r4;
      WVt2[(size_t)hh * 262144 + (size_t)(ff * 64 + g) * 64 + hp2] = (bf16)ld[hp2 * 65 + ff];
    }
    return;
  }
  bid -= 512;
  {  // LayerNorm row r = bid
    int r = bid;
    const float* xr = x + (size_t)r * 512;
    float v0 = xr[tid], v1 = xr[tid + 256];
    float s = v0 + v1, s2 = v0 * v0 + v1 * v1;
#pragma unroll
    for (int off = 32; off > 0; off >>= 1) {
      s += __shfl_down(s, off);
      s2 += __shfl_down(s2, off);
    }
    __shared__ float redS[4], redS2[4];
    int wave = tid >> 6, lane = tid & 63;
    if (lane == 0) { redS[wave] = s; redS2[wave] = s2; }
    __syncthreads();
    float S = redS[0] + redS[1] + redS[2] + redS[3];
    float S2 = redS2[0] + redS2[1] + redS2[2] + redS2[3];
    float mean = S * (1.0f / 512.0f);
    float var = S2 * (1.0f / 512.0f) - mean * mean;
    float rstd = rsqrtf(var + 1e-5f);
    bf16* xnr = xn_bf + (size_t)r * 512;
    xnr[tid] = (bf16)((v0 - mean) * rstd * ln_w[tid] + ln_b[tid]);
    xnr[tid + 256] = (bf16)((v1 - mean) * rstd * ln_w[tid + 256] + ln_b[tid + 256]);
  }
}

// =================== LDS-free bf16 MFMA GEMM core (C = A @ Bt^T) ===================
template <int MODE>
__device__ __forceinline__ void gemm_body(const bf16* __restrict__ A, const bf16* __restrict__ Bt,
                                          bf16* __restrict__ C1, int N, int K,
                                          int nb, int mb, int tid) {
  int n0 = nb * 64, m0 = mb * 64;
  int wave = tid >> 6, lane = tid & 63;
  int lq = lane >> 4, l16 = lane & 15;
  const bf16* Ap = A + (size_t)(m0 + wave * 16 + l16) * K;
  f32x4 acc[4];
#pragma unroll
  for (int nt = 0; nt < 4; nt++) acc[nt] = (f32x4){0.f, 0.f, 0.f, 0.f};
  for (int k0 = 0; k0 < K; k0 += 32) {
    bf16x8 af = *(const bf16x8*)(Ap + k0 + lq * 8);
#pragma unroll
    for (int nt = 0; nt < 4; nt++) {
      bf16x8 bv = *(const bf16x8*)(Bt + (size_t)(n0 + nt * 16 + l16) * K + k0 + lq * 8);
      acc[nt] = MFMA_BF16(af, bv, acc[nt]);
    }
  }
  int cm = m0 + wave * 16 + lq * 4;
#pragma unroll
  for (int nt = 0; nt < 4; nt++) {
    int n = n0 + nt * 16 + l16;
    if constexpr (MODE == 1) {
#pragma unroll
      for (int rg = 0; rg < 4; rg++) C1[(size_t)(cm + rg) * N + n] = (bf16)acc[nt][rg];
    } else {
      int r = cm >> 6, i0 = cm & 63;
      bf16x4 pk = {(bf16)acc[nt][0], (bf16)acc[nt][1], (bf16)acc[nt][2], (bf16)acc[nt][3]};
      *(bf16x4*)(C1 + (size_t)r * 12288 + (size_t)n * 64 + i0) = pk;
    }
  }
}

// =================== K2: proj GEMM (inline f32 weight cvt) + slice epilogue ===================
__global__ __launch_bounds__(256) void k2_proj(
    const bf16* __restrict__ xn_bf, const float* __restrict__ Wab,
    const float* __restrict__ b_abcde, float* __restrict__ proj, bf16* __restrict__ a_bf,
    bf16* __restrict__ c_bf, bf16* __restrict__ d_bf) {
  int bid = blockIdx.x, tid = threadIdx.x;
  int nb = bid % 40, mb = bid / 40;
  int n0 = nb * 64, m0 = mb * 64;
  int wave = tid >> 6, lane = tid & 63;
  int lq = lane >> 4, l16 = lane & 15;
  const bf16* Ap = xn_bf + (size_t)(m0 + wave * 16 + l16) * 512;
  f32x4 acc[4];
#pragma unroll
  for (int nt = 0; nt < 4; nt++) acc[nt] = (f32x4){0.f, 0.f, 0.f, 0.f};
  for (int k0 = 0; k0 < 512; k0 += 32) {
    bf16x8 af = *(const bf16x8*)(Ap + k0 + lq * 8);
#pragma unroll
    for (int nt = 0; nt < 4; nt++) {
      f32x8 wv = *(const f32x8*)(Wab + (size_t)(n0 + nt * 16 + l16) * 512 + k0 + lq * 8);
      acc[nt] = MFMA_BF16(af, cvt8(wv), acc[nt]);
    }
  }
  int cm = m0 + wave * 16 + lq * 4;
#pragma unroll
  for (int nt = 0; nt < 4; nt++) {
    int n = n0 + nt * 16 + l16;
    int chunk = n >> 9, hcol = (n >> 6) & 7, i = n & 63;
#pragma unroll
    for (int rg = 0; rg < 4; rg++) {
      int m = cm + rg;
      float v = acc[nt][rg] + b_abcde[n];
      proj[(size_t)m * 2560 + n] = v;
      bf16 bv = (bf16)v;
      if (chunk == 0) a_bf[((size_t)hcol * SEQ + m) * 64 + i] = bv;
      else if (chunk == 2) c_bf[(size_t)m * 512 + (n - 1024)] = bv;
      else if (chunk == 3) d_bf[((size_t)hcol * SEQ + m) * 64 + i] = bv;
    }
  }
}

// =================== K3: step1 GEMM (inline WK cvt) + t GEMM + eT/ecum + bsum ===================
__global__ __launch_bounds__(256) void k3_mid(
    const bf16* __restrict__ c_bf, const float* __restrict__ WK, bf16* __restrict__ s1bf,
    const bf16* __restrict__ d_bf, const bf16* __restrict__ WVt2, bf16* __restrict__ tTt,
    const float* __restrict__ proj, bf16* __restrict__ eT_bf, float* __restrict__ ecum,
    bf16* __restrict__ bsum_bf) {
  __shared__ float el[64 * 65];
  int bid = blockIdx.x, tid = threadIdx.x;
  if (bid < 192) {  // step1: [192 x 4096] = c @ WK2t^T, K=512, B read from WK f32 directly
    int nb = bid % 64, mb = bid / 64;
    int n0 = nb * 64, m0 = mb * 64;
    int wave = tid >> 6, lane = tid & 63;
    int lq = lane >> 4, l16 = lane & 15;
    const bf16* Ap = c_bf + (size_t)(m0 + wave * 16 + l16) * 512;
    f32x4 acc[4];
#pragma unroll
    for (int nt = 0; nt < 4; nt++) acc[nt] = (f32x4){0.f, 0.f, 0.f, 0.f};
    size_t offn[4];
#pragma unroll
    for (int nt = 0; nt < 4; nt++) {
      int n = n0 + nt * 16 + l16;  // n = i*64 + j
      offn[nt] = (size_t)(n >> 6) * 4096 + (size_t)(n & 63) * 64;
    }
    for (int k0 = 0; k0 < 512; k0 += 32) {
      bf16x8 af = *(const bf16x8*)(Ap + k0 + lq * 8);
      size_t kb = (size_t)(k0 >> 6) * 262144 + (k0 & 32) + lq * 8;
#pragma unroll
      for (int nt = 0; nt < 4; nt++) {
        f32x8 wv = *(const f32x8*)(WK + kb + offn[nt]);
        acc[nt] = MFMA_BF16(af, cvt8(wv), acc[nt]);
      }
    }
    int cm = m0 + wave * 16 + lq * 4;
#pragma unroll
    for (int nt = 0; nt < 4; nt++) {
      int n = n0 + nt * 16 + l16;
#pragma unroll
      for (int rg = 0; rg < 4; rg++) s1bf[(size_t)(cm + rg) * 4096 + n] = (bf16)acc[nt][rg];
    }
    return;
  }
  bid -= 192;
  if (bid < 1536) {  // t[h]: [192 x 4096] = d_h @ WVt2[h]^T, K=64 -> row-major == tTt layout
    int h = bid / 192, rem = bid % 192;
    gemm_body<1>(d_bf + (size_t)h * 12288, WVt2 + (size_t)h * 262144,
                 tTt + (size_t)h * 786432, 4096, 64, rem % 64, rem / 64, tid);
    return;
  }
  bid -= 1536;
  if (bid < 8) {  // per-head: eT transpose + ecum prefix scan, 64-row chunks with carry
    int h = bid;
    float carry = 0.f;
    for (int ch = 0; ch < 3; ch++) {
      int pbase = ch * 64;
      for (int idx = tid; idx < 4096; idx += 256) {
        int pl = idx >> 6, g = idx & 63;
        el[pl * 65 + g] = proj[(size_t)(pbase + pl) * 2560 + 2048 + h * 64 + g];
      }
      __syncthreads();
      for (int idx = tid; idx < 4096; idx += 256) {
        int g = idx >> 6, ql = idx & 63;
        eT_bf[((size_t)h * 64 + g) * SEQ + pbase + ql] = (bf16)el[ql * 65 + g];
      }
      if (tid < 64) {
        float run = carry;
        for (int pl = 0; pl < 64; pl++) {
          run += el[pl * 65 + tid];
          ecum[(size_t)h * 12288 + (pbase + pl) * 64 + tid] = run;
        }
        carry = run;
      }
      __syncthreads();
    }
    return;
  }
  bid -= 8;
  {  // bsum[q][j] = sum_h b[q,h,j] -> bf16 ; 3 blocks x 64 q
    int j = tid & 63, qg = tid >> 6;
#pragma unroll
    for (int qi = 0; qi < 16; qi++) {
      int q = bid * 64 + qg * 16 + qi;
      float s = 0.f;
#pragma unroll
      for (int hh = 0; hh < 8; hh++) s += proj[(size_t)q * 2560 + 512 + hh * 64 + j];
      bsum_bf[q * 64 + j] = (bf16)s;
    }
  }
}

// =================== K4: step2 GEMM -> s2bf[r][q][i] ===================
__global__ __launch_bounds__(256) void k4_step2(const bf16* __restrict__ s1bf,
                                                const bf16* __restrict__ bsum_bf,
                                                bf16* __restrict__ s2bf) {
  int bid = blockIdx.x;
  gemm_body<2>(s1bf, bsum_bf, s2bf, 192, 64, bid % 3, bid / 3, threadIdx.x);
}

// =================== K5: scores+exp+ew(+ecum) per (r,h) — ILP-batched ===================
// Per c-chunk: ALL 6 score subtiles (12 indep MFMAs) -> ALL exps -> per-mt LDS bufs
// (parity double-buffered) -> ALL 12 ew MFMAs. No serializing single-buffer chain.
__global__ __launch_bounds__(256, 3) void k5_attn(
    const bf16* __restrict__ a_bf, const bf16* __restrict__ s2bf,
    const bf16* __restrict__ eT_bf, const float* __restrict__ ecum,
    bf16* __restrict__ ew_bf, float* __restrict__ Lsum) {
  int r = blockIdx.x, h = blockIdx.y;
  int tid = threadIdx.x, wave = tid >> 6, lane = tid & 63;
  int lq = lane >> 4, l16 = lane & 15;
  __shared__ __align__(16) bf16 wch[2][4][3][16 * 40];  // 30.7 KB
  __shared__ float redL[4];
  int pt[3] = {wave, wave + 4, 11 - wave};

  const bf16* ah = a_bf + (size_t)h * 12288;
  const bf16* s2r = s2bf + (size_t)r * 12288;
  const bf16* eh = eT_bf + (size_t)h * 12288;
  const float* ech = ecum + (size_t)h * 12288;

  bf16x8 afr[3][2];
#pragma unroll
  for (int mt = 0; mt < 3; mt++)
#pragma unroll
    for (int kc = 0; kc < 2; kc++)
      afr[mt][kc] = *(const bf16x8*)(ah + (pt[mt] * 16 + l16) * 64 + kc * 32 + lq * 8);

  f32x4 ewacc[3][4];
#pragma unroll
  for (int mt = 0; mt < 3; mt++)
#pragma unroll
    for (int nt = 0; nt < 4; nt++) ewacc[mt][nt] = (f32x4){0.f, 0.f, 0.f, 0.f};
  float lpart = 0.f;

  for (int c = 0; c < 6; c++) {
    if (c * 32 + 31 <= wave * 16) continue;  // whole wave masked for this chunk
    int par = c & 1;
    bf16x8 efr[4];
#pragma unroll
    for (int nt = 0; nt < 4; nt++)
      efr[nt] = *(const bf16x8*)(eh + (nt * 16 + l16) * SEQ + c * 32 + lq * 8);
    bf16x8 bq[2][2];
#pragma unroll
    for (int sub = 0; sub < 2; sub++) {
      int q = c * 32 + sub * 16 + l16;
      bq[sub][0] = *(const bf16x8*)(s2r + q * 64 + lq * 8);
      bq[sub][1] = *(const bf16x8*)(s2r + q * 64 + 32 + lq * 8);
    }
    // ---- phase 1: all score MFMAs (independent) ----
    f32x4 sacc[3][2];
#pragma unroll
    for (int mt = 0; mt < 3; mt++) {
      if (c * 32 + 31 <= pt[mt] * 16) continue;  // mt fully masked this chunk
#pragma unroll
      for (int sub = 0; sub < 2; sub++) {
        if (c * 32 + sub * 16 + 15 <= pt[mt] * 16) continue;  // sub fully masked
        f32x4 sv = (f32x4){0.f, 0.f, 0.f, 0.f};
        sv = MFMA_BF16(afr[mt][0], bq[sub][0], sv);
        sacc[mt][sub] = MFMA_BF16(afr[mt][1], bq[sub][1], sv);
      }
    }
    // ---- phase 2: all exps + LDS stores (per-mt buffers) ----
#pragma unroll
    for (int mt = 0; mt < 3; mt++) {
      if (c * 32 + 31 <= pt[mt] * 16) continue;
      bf16* mybuf = &wch[par][wave][mt][0];
#pragma unroll
      for (int sub = 0; sub < 2; sub++) {
        if (c * 32 + sub * 16 + 15 <= pt[mt] * 16) {
#pragma unroll
          for (int rg = 0; rg < 4; rg++) mybuf[(lq * 4 + rg) * 40 + sub * 16 + l16] = (bf16)0.f;
          continue;
        }
        int q = c * 32 + sub * 16 + l16;
        int p0 = pt[mt] * 16 + lq * 4;
#pragma unroll
        for (int rg = 0; rg < 4; rg++) {
          float wv = (q > p0 + rg) ? __expf(sacc[mt][sub][rg] * 0.015625f) : 0.f;
          lpart += wv;
          mybuf[(lq * 4 + rg) * 40 + sub * 16 + l16] = (bf16)wv;
        }
      }
    }
    // ---- phase 3: all ew MFMAs ----
#pragma unroll
    for (int mt = 0; mt < 3; mt++) {
      if (c * 32 + 31 <= pt[mt] * 16) continue;
      bf16x8 wf = *(const bf16x8*)(&wch[par][wave][mt][l16 * 40 + lq * 8]);
#pragma unroll
      for (int nt = 0; nt < 4; nt++) ewacc[mt][nt] = MFMA_BF16(wf, efr[nt], ewacc[mt][nt]);
    }
  }

  bf16* ewout = ew_bf + ((size_t)h * SEQ + r) * 12288;
#pragma unroll
  for (int mt = 0; mt < 3; mt++)
#pragma unroll
    for (int nt = 0; nt < 4; nt++)
#pragma unroll
      for (int rg = 0; rg < 4; rg++) {
        int p = pt[mt] * 16 + lq * 4 + rg;
        int g = nt * 16 + l16;
        ewout[p * 64 + g] = (bf16)(ewacc[mt][nt][rg] + ech[p * 64 + g]);
      }

#pragma unroll
  for (int off = 32; off > 0; off >>= 1) lpart += __shfl_down(lpart, off);
  if (lane == 0) redL[wave] = lpart;
  __syncthreads();
  if (tid == 0) Lsum[h * SEQ + r] = redL[0] + redL[1] + redL[2] + redL[3];
}

// =================== K5b: Zpart[ks][r][h*64+f] = ew'[h,32r,kslice] @ tTt[h,kslice] ===================
// grid (8 h, 6 mt32, 8 ks); 512 thr = 8 waves; 32 r-rows per block halves t re-reads.
__global__ __launch_bounds__(512) void k5b_z(
    const bf16* __restrict__ ew_bf, const bf16* __restrict__ tTt, float* __restrict__ Zpart) {
  int h = blockIdx.x, mt = blockIdx.y, ks = blockIdx.z;
  int tid = threadIdx.x, wave = tid >> 6, lane = tid & 63;
  int lq = lane >> 4, l16 = lane & 15;
  __shared__ float zred[8][16][66];
  const bf16* ewh = ew_bf + ((size_t)h * SEQ + mt * 32) * 12288;
  const bf16* th = tTt + (size_t)h * 786432;
  f32x4 acc[2][4];
#pragma unroll
  for (int m2 = 0; m2 < 2; m2++)
#pragma unroll
    for (int nt = 0; nt < 4; nt++) acc[m2][nt] = (f32x4){0.f, 0.f, 0.f, 0.f};
  for (int jj = 0; jj < 6; jj++) {
    int kc = ks * 48 + wave * 6 + jj;  // 32-wide k chunk
    int p = kc >> 1, g0 = (kc & 1) * 32;
    bf16x8 af0 = *(const bf16x8*)(ewh + (size_t)l16 * 12288 + kc * 32 + lq * 8);
    bf16x8 af1 = *(const bf16x8*)(ewh + (size_t)(16 + l16) * 12288 + kc * 32 + lq * 8);
#pragma unroll
    for (int nt = 0; nt < 4; nt++) {
      bf16x8 tf = *(const bf16x8*)(th + (size_t)p * 4096 + (nt * 16 + l16) * 64 + g0 + lq * 8);
      acc[0][nt] = MFMA_BF16(af0, tf, acc[0][nt]);
      acc[1][nt] = MFMA_BF16(af1, tf, acc[1][nt]);
    }
  }
#pragma unroll
  for (int m2 = 0; m2 < 2; m2++) {
    if (m2) __syncthreads();
#pragma unroll
    for (int nt = 0; nt < 4; nt++)
#pragma unroll
      for (int rg = 0; rg < 4; rg++) zred[wave][lq * 4 + rg][nt * 16 + l16] = acc[m2][nt][rg];
    __syncthreads();
#pragma unroll
    for (int o = 0; o < 2; o++) {
      int idx = o * 512 + tid;  // 1024 outputs: [rloc 16][f 64]
      int rloc = idx >> 6, f = idx & 63;
      float s = 0.f;
#pragma unroll
      for (int wv = 0; wv < 8; wv++) s += zred[wv][rloc][f];
      Zpart[(size_t)ks * 98304 + (size_t)(mt * 32 + m2 * 16 + rloc) * 512 + h * 64 + f] = s;
    }
  }
}

// =================== K6: out = z @ Wout^T + b_out; z built inline from Zpart/Lsum ===================
__global__ __launch_bounds__(256) void k6_out(
    const float* __restrict__ Zpart, const float* __restrict__ Lsum,
    const float* __restrict__ Wout, const float* __restrict__ b_out, float* __restrict__ out) {
  int bid = blockIdx.x, tid = threadIdx.x;
  int nb = bid & 7, mb = bid >> 3;
  int n0 = nb * 64, m0 = mb * 64;
  int wave = tid >> 6, lane = tid & 63;
  int lq = lane >> 4, l16 = lane & 15;
  int m = m0 + wave * 16 + l16;
  f32x4 acc[4];
#pragma unroll
  for (int nt = 0; nt < 4; nt++) acc[nt] = (f32x4){0.f, 0.f, 0.f, 0.f};
  for (int k0 = 0; k0 < 512; k0 += 32) {
    int h = k0 >> 6;
    float L = Lsum[h * SEQ + m] + 18528.0f;  // 18528 masked (p>=q) entries, weight exactly 1.0f
    float rL = 1.0f / L;
    size_t zo = (size_t)m * 512 + k0 + lq * 8;
    f32x8 s = *(const f32x8*)(Zpart + zo);
#pragma unroll
    for (int ks = 1; ks < 8; ks++) s += *(const f32x8*)(Zpart + (size_t)ks * 98304 + zo);
    bf16x8 af = cvt8(s * rL);
#pragma unroll
    for (int nt = 0; nt < 4; nt++) {
      f32x8 wv = *(const f32x8*)(Wout + (size_t)(n0 + nt * 16 + l16) * 512 + k0 + lq * 8);
      acc[nt] = MFMA_BF16(af, cvt8(wv), acc[nt]);
    }
  }
  int cm = m0 + wave * 16 + lq * 4;
#pragma unroll
  for (int nt = 0; nt < 4; nt++) {
    int n = n0 + nt * 16 + l16;
    float bv = b_out[n];
#pragma unroll
    for (int rg = 0; rg < 4; rg++) out[(size_t)(cm + rg) * 512 + n] = acc[nt][rg] + bv;
  }
}

// =================== workspace layout (f32 units) ===================
static const size_t OFF_PROJ = 0;         // f32 491520
static const size_t OFF_ECUM = 491520;    // f32 98304
static const size_t OFF_XN = 589824;      // bf16 -> 49152
static const size_t OFF_ZPART = 638976;   // f32 786432 (8 slices x 98304)
static const size_t OFF_LSUM = 1425408;   // f32 1536
static const size_t OFF_WVT = 2473984;    // bf16 -> 1048576
static const size_t OFF_A = 3522560;      // bf16 -> 49152
static const size_t OFF_C = 3571712;      // 49152
static const size_t OFF_D = 3620864;      // 49152
static const size_t OFF_ET = 3670016;     // 49152
static const size_t OFF_BSUM = 3719168;   // 6144
static const size_t OFF_S1 = 3725312;     // bf16 -> 393216
static const size_t OFF_S2 = 4118528;     // bf16 -> 1179648
static const size_t OFF_TT = 5298176;     // bf16 -> 3145728
static const size_t OFF_EW = 8493056;     // bf16 -> 9437184
// TOTAL = 17930240 f32 = 71.7 MB

extern "C" void kernel_launch(void* const* d_in, const int* in_sizes, int n_in,
                              void* d_out, int out_size, void* d_ws, size_t ws_size,
                              hipStream_t stream) {
  (void)in_sizes; (void)n_in; (void)out_size; (void)ws_size;
  const float* x = (const float*)d_in[0];
  const float* ln_w = (const float*)d_in[1];
  const float* ln_b = (const float*)d_in[2];
  const float* W_abcde = (const float*)d_in[3];
  const float* b_abcde = (const float*)d_in[4];
  const float* W_K = (const float*)d_in[5];
  const float* W_V = (const float*)d_in[6];
  const float* W_out = (const float*)d_in[7];
  const float* b_out = (const float*)d_in[8];
  float* out = (float*)d_out;
  float* ws = (float*)d_ws;

  float* proj = ws + OFF_PROJ;
  float* ecum = ws + OFF_ECUM;
  bf16* xn_bf = (bf16*)(ws + OFF_XN);
  float* Zpart = ws + OFF_ZPART;
  float* Lsum = ws + OFF_LSUM;
  bf16* WVt2 = (bf16*)(ws + OFF_WVT);
  bf16* a_bf = (bf16*)(ws + OFF_A);
  bf16* c_bf = (bf16*)(ws + OFF_C);
  bf16* d_bf = (bf16*)(ws + OFF_D);
  bf16* eT_bf = (bf16*)(ws + OFF_ET);
  bf16* bsum_bf = (bf16*)(ws + OFF_BSUM);
  bf16* s1bf = (bf16*)(ws + OFF_S1);
  bf16* s2bf = (bf16*)(ws + OFF_S2);
  bf16* tTt = (bf16*)(ws + OFF_TT);
  bf16* ew_bf = (bf16*)(ws + OFF_EW);

  k1_prep<<<704, 256, 0, stream>>>(x, ln_w, ln_b, W_V, xn_bf, WVt2);
  k2_proj<<<120, 256, 0, stream>>>(xn_bf, W_abcde, b_abcde, proj, a_bf, c_bf, d_bf);
  k3_mid<<<1739, 256, 0, stream>>>(c_bf, W_K, s1bf, d_bf, WVt2, tTt, proj, eT_bf, ecum,
                                   bsum_bf);
  k4_step2<<<576, 256, 0, stream>>>(s1bf, bsum_bf, s2bf);
  k5_attn<<<dim3(SEQ, 8), 256, 0, stream>>>(a_bf, s2bf, eT_bf, ecum, ew_bf, Lsum);
  k5b_z<<<dim3(8, 6, 8), 512, 0, stream>>>(ew_bf, tTt, Zpart);
  k6_out<<<24, 256, 0, stream>>>(Zpart, Lsum, W_out, b_out, out);
}

// Round 8
// 214.857 us; speedup vs baseline: 1.1906x; 1.1906x over previous
//
#include <hip/hip_runtime.h>
#include <hip/hip_bf16.h>
#include <cstdint>

#define SEQ 192

typedef float f32x4 __attribute__((ext_vector_type(4)));
typedef float f32x8 __attribute__((ext_vector_type(8)));
typedef __bf16 bf16;
typedef __bf16 bf16x8 __attribute__((ext_vector_type(8)));
typedef __bf16 bf16x4 __attribute__((ext_vector_type(4)));

#define MFMA_BF16(a, b, c) __builtin_amdgcn_mfma_f32_16x16x32_bf16(a, b, c, 0, 0, 0)

__device__ __forceinline__ bf16x8 cvt8(f32x8 v) {
  bf16x8 o;
#pragma unroll
  for (int i = 0; i < 8; i++) o[i] = (bf16)v[i];
  return o;
}

// =================== K1: WVt2 transpose + LayerNorm ===================
// WVt2[h][(f*64+g)*64 + h'] = WV[h][h'][g][f]  (so row-major t == consumer layout)
__global__ __launch_bounds__(256) void k1_prep(
    const float* __restrict__ x, const float* __restrict__ ln_w, const float* __restrict__ ln_b,
    const float* __restrict__ WV, bf16* __restrict__ xn_bf, bf16* __restrict__ WVt2) {
  int bid = blockIdx.x, tid = threadIdx.x;
  if (bid < 512) {
    int g = bid & 63, hh = bid >> 6;
    __shared__ float ld[64 * 65];
    int f = tid & 63, r4 = tid >> 6;
#pragma unroll
    for (int it = 0; it < 16; it++) {
      int hp = it * 4 + r4;
      ld[hp * 65 + f] = WV[(((size_t)(hh * 64 + hp) * 64 + g) * 64) + f];
    }
    __syncthreads();
    int hp2 = tid & 63;
#pragma unroll
    for (int it = 0; it < 16; it++) {
      int ff = it * 4 + r4;
      WVt2[(size_t)hh * 262144 + (size_t)(ff * 64 + g) * 64 + hp2] = (bf16)ld[hp2 * 65 + ff];
    }
    return;
  }
  bid -= 512;
  {  // LayerNorm row r = bid
    int r = bid;
    const float* xr = x + (size_t)r * 512;
    float v0 = xr[tid], v1 = xr[tid + 256];
    float s = v0 + v1, s2 = v0 * v0 + v1 * v1;
#pragma unroll
    for (int off = 32; off > 0; off >>= 1) {
      s += __shfl_down(s, off);
      s2 += __shfl_down(s2, off);
    }
    __shared__ float redS[4], redS2[4];
    int wave = tid >> 6, lane = tid & 63;
    if (lane == 0) { redS[wave] = s; redS2[wave] = s2; }
    __syncthreads();
    float S = redS[0] + redS[1] + redS[2] + redS[3];
    float S2 = redS2[0] + redS2[1] + redS2[2] + redS2[3];
    float mean = S * (1.0f / 512.0f);
    float var = S2 * (1.0f / 512.0f) - mean * mean;
    float rstd = rsqrtf(var + 1e-5f);
    bf16* xnr = xn_bf + (size_t)r * 512;
    xnr[tid] = (bf16)((v0 - mean) * rstd * ln_w[tid] + ln_b[tid]);
    xnr[tid + 256] = (bf16)((v1 - mean) * rstd * ln_w[tid + 256] + ln_b[tid + 256]);
  }
}

// =================== LDS-free bf16 MFMA GEMM core (C = A @ Bt^T) ===================
template <int MODE>
__device__ __forceinline__ void gemm_body(const bf16* __restrict__ A, const bf16* __restrict__ Bt,
                                          bf16* __restrict__ C1, int N, int K,
                                          int nb, int mb, int tid) {
  int n0 = nb * 64, m0 = mb * 64;
  int wave = tid >> 6, lane = tid & 63;
  int lq = lane >> 4, l16 = lane & 15;
  const bf16* Ap = A + (size_t)(m0 + wave * 16 + l16) * K;
  f32x4 acc[4];
#pragma unroll
  for (int nt = 0; nt < 4; nt++) acc[nt] = (f32x4){0.f, 0.f, 0.f, 0.f};
  for (int k0 = 0; k0 < K; k0 += 32) {
    bf16x8 af = *(const bf16x8*)(Ap + k0 + lq * 8);
#pragma unroll
    for (int nt = 0; nt < 4; nt++) {
      bf16x8 bv = *(const bf16x8*)(Bt + (size_t)(n0 + nt * 16 + l16) * K + k0 + lq * 8);
      acc[nt] = MFMA_BF16(af, bv, acc[nt]);
    }
  }
  int cm = m0 + wave * 16 + lq * 4;
#pragma unroll
  for (int nt = 0; nt < 4; nt++) {
    int n = n0 + nt * 16 + l16;
    if constexpr (MODE == 1) {
#pragma unroll
      for (int rg = 0; rg < 4; rg++) C1[(size_t)(cm + rg) * N + n] = (bf16)acc[nt][rg];
    } else {
      int r = cm >> 6, i0 = cm & 63;
      bf16x4 pk = {(bf16)acc[nt][0], (bf16)acc[nt][1], (bf16)acc[nt][2], (bf16)acc[nt][3]};
      *(bf16x4*)(C1 + (size_t)r * 12288 + (size_t)n * 64 + i0) = pk;
    }
  }
}

// =================== K2: proj GEMM (inline f32 weight cvt) + slice epilogue ===================
__global__ __launch_bounds__(256) void k2_proj(
    const bf16* __restrict__ xn_bf, const float* __restrict__ Wab,
    const float* __restrict__ b_abcde, float* __restrict__ proj, bf16* __restrict__ a_bf,
    bf16* __restrict__ c_bf, bf16* __restrict__ d_bf) {
  int bid = blockIdx.x, tid = threadIdx.x;
  int nb = bid % 40, mb = bid / 40;
  int n0 = nb * 64, m0 = mb * 64;
  int wave = tid >> 6, lane = tid & 63;
  int lq = lane >> 4, l16 = lane & 15;
  const bf16* Ap = xn_bf + (size_t)(m0 + wave * 16 + l16) * 512;
  f32x4 acc[4];
#pragma unroll
  for (int nt = 0; nt < 4; nt++) acc[nt] = (f32x4){0.f, 0.f, 0.f, 0.f};
  for (int k0 = 0; k0 < 512; k0 += 32) {
    bf16x8 af = *(const bf16x8*)(Ap + k0 + lq * 8);
#pragma unroll
    for (int nt = 0; nt < 4; nt++) {
      f32x8 wv = *(const f32x8*)(Wab + (size_t)(n0 + nt * 16 + l16) * 512 + k0 + lq * 8);
      acc[nt] = MFMA_BF16(af, cvt8(wv), acc[nt]);
    }
  }
  int cm = m0 + wave * 16 + lq * 4;
#pragma unroll
  for (int nt = 0; nt < 4; nt++) {
    int n = n0 + nt * 16 + l16;
    int chunk = n >> 9, hcol = (n >> 6) & 7, i = n & 63;
#pragma unroll
    for (int rg = 0; rg < 4; rg++) {
      int m = cm + rg;
      float v = acc[nt][rg] + b_abcde[n];
      proj[(size_t)m * 2560 + n] = v;
      bf16 bv = (bf16)v;
      if (chunk == 0) a_bf[((size_t)hcol * SEQ + m) * 64 + i] = bv;
      else if (chunk == 2) c_bf[(size_t)m * 512 + (n - 1024)] = bv;
      else if (chunk == 3) d_bf[((size_t)hcol * SEQ + m) * 64 + i] = bv;
    }
  }
}

// =================== K3: step1 GEMM (inline WK cvt) + t GEMM + eT/ecum + bsum ===================
__global__ __launch_bounds__(256) void k3_mid(
    const bf16* __restrict__ c_bf, const float* __restrict__ WK, bf16* __restrict__ s1bf,
    const bf16* __restrict__ d_bf, const bf16* __restrict__ WVt2, bf16* __restrict__ tTt,
    const float* __restrict__ proj, bf16* __restrict__ eT_bf, float* __restrict__ ecum,
    bf16* __restrict__ bsum_bf) {
  __shared__ float el[64 * 65];
  int bid = blockIdx.x, tid = threadIdx.x;
  if (bid < 192) {  // step1: [192 x 4096] = c @ WK2t^T, K=512, B read from WK f32 directly
    int nb = bid % 64, mb = bid / 64;
    int n0 = nb * 64, m0 = mb * 64;
    int wave = tid >> 6, lane = tid & 63;
    int lq = lane >> 4, l16 = lane & 15;
    const bf16* Ap = c_bf + (size_t)(m0 + wave * 16 + l16) * 512;
    f32x4 acc[4];
#pragma unroll
    for (int nt = 0; nt < 4; nt++) acc[nt] = (f32x4){0.f, 0.f, 0.f, 0.f};
    size_t offn[4];
#pragma unroll
    for (int nt = 0; nt < 4; nt++) {
      int n = n0 + nt * 16 + l16;  // n = i*64 + j
      offn[nt] = (size_t)(n >> 6) * 4096 + (size_t)(n & 63) * 64;
    }
    for (int k0 = 0; k0 < 512; k0 += 32) {
      bf16x8 af = *(const bf16x8*)(Ap + k0 + lq * 8);
      size_t kb = (size_t)(k0 >> 6) * 262144 + (k0 & 32) + lq * 8;
#pragma unroll
      for (int nt = 0; nt < 4; nt++) {
        f32x8 wv = *(const f32x8*)(WK + kb + offn[nt]);
        acc[nt] = MFMA_BF16(af, cvt8(wv), acc[nt]);
      }
    }
    int cm = m0 + wave * 16 + lq * 4;
#pragma unroll
    for (int nt = 0; nt < 4; nt++) {
      int n = n0 + nt * 16 + l16;
#pragma unroll
      for (int rg = 0; rg < 4; rg++) s1bf[(size_t)(cm + rg) * 4096 + n] = (bf16)acc[nt][rg];
    }
    return;
  }
  bid -= 192;
  if (bid < 1536) {  // t[h]: [192 x 4096] = d_h @ WVt2[h]^T, K=64 -> row-major == tTt layout
    int h = bid / 192, rem = bid % 192;
    gemm_body<1>(d_bf + (size_t)h * 12288, WVt2 + (size_t)h * 262144,
                 tTt + (size_t)h * 786432, 4096, 64, rem % 64, rem / 64, tid);
    return;
  }
  bid -= 1536;
  if (bid < 8) {  // per-head: eT transpose + ecum prefix scan, 64-row chunks with carry
    int h = bid;
    float carry = 0.f;
    for (int ch = 0; ch < 3; ch++) {
      int pbase = ch * 64;
      for (int idx = tid; idx < 4096; idx += 256) {
        int pl = idx >> 6, g = idx & 63;
        el[pl * 65 + g] = proj[(size_t)(pbase + pl) * 2560 + 2048 + h * 64 + g];
      }
      __syncthreads();
      for (int idx = tid; idx < 4096; idx += 256) {
        int g = idx >> 6, ql = idx & 63;
        eT_bf[((size_t)h * 64 + g) * SEQ + pbase + ql] = (bf16)el[ql * 65 + g];
      }
      if (tid < 64) {
        float run = carry;
        for (int pl = 0; pl < 64; pl++) {
          run += el[pl * 65 + tid];
          ecum[(size_t)h * 12288 + (pbase + pl) * 64 + tid] = run;
        }
        carry = run;
      }
      __syncthreads();
    }
    return;
  }
  bid -= 8;
  {  // bsum[q][j] = sum_h b[q,h,j] -> bf16 ; 3 blocks x 64 q
    int j = tid & 63, qg = tid >> 6;
#pragma unroll
    for (int qi = 0; qi < 16; qi++) {
      int q = bid * 64 + qg * 16 + qi;
      float s = 0.f;
#pragma unroll
      for (int hh = 0; hh < 8; hh++) s += proj[(size_t)q * 2560 + 512 + hh * 64 + j];
      bsum_bf[q * 64 + j] = (bf16)s;
    }
  }
}

// =================== K4: step2 GEMM -> s2bf[r][q][i] ===================
__global__ __launch_bounds__(256) void k4_step2(const bf16* __restrict__ s1bf,
                                                const bf16* __restrict__ bsum_bf,
                                                bf16* __restrict__ s2bf) {
  int bid = blockIdx.x;
  gemm_body<2>(s1bf, bsum_bf, s2bf, 192, 64, bid % 3, bid / 3, threadIdx.x);
}

// =================== K5: scores+exp+ew(+ecum) per (r,h) — ILP-batched ===================
__global__ __launch_bounds__(256, 3) void k5_attn(
    const bf16* __restrict__ a_bf, const bf16* __restrict__ s2bf,
    const bf16* __restrict__ eT_bf, const float* __restrict__ ecum,
    bf16* __restrict__ ew_bf, float* __restrict__ Lsum) {
  int r = blockIdx.x, h = blockIdx.y;
  int tid = threadIdx.x, wave = tid >> 6, lane = tid & 63;
  int lq = lane >> 4, l16 = lane & 15;
  __shared__ __align__(16) bf16 wch[2][4][3][16 * 40];  // 30.7 KB
  __shared__ float redL[4];
  int pt[3] = {wave, wave + 4, 11 - wave};

  const bf16* ah = a_bf + (size_t)h * 12288;
  const bf16* s2r = s2bf + (size_t)r * 12288;
  const bf16* eh = eT_bf + (size_t)h * 12288;
  const float* ech = ecum + (size_t)h * 12288;

  bf16x8 afr[3][2];
#pragma unroll
  for (int mt = 0; mt < 3; mt++)
#pragma unroll
    for (int kc = 0; kc < 2; kc++)
      afr[mt][kc] = *(const bf16x8*)(ah + (pt[mt] * 16 + l16) * 64 + kc * 32 + lq * 8);

  f32x4 ewacc[3][4];
#pragma unroll
  for (int mt = 0; mt < 3; mt++)
#pragma unroll
    for (int nt = 0; nt < 4; nt++) ewacc[mt][nt] = (f32x4){0.f, 0.f, 0.f, 0.f};
  float lpart = 0.f;

  for (int c = 0; c < 6; c++) {
    if (c * 32 + 31 <= wave * 16) continue;  // whole wave masked for this chunk
    int par = c & 1;
    bf16x8 efr[4];
#pragma unroll
    for (int nt = 0; nt < 4; nt++)
      efr[nt] = *(const bf16x8*)(eh + (nt * 16 + l16) * SEQ + c * 32 + lq * 8);
    bf16x8 bq[2][2];
#pragma unroll
    for (int sub = 0; sub < 2; sub++) {
      int q = c * 32 + sub * 16 + l16;
      bq[sub][0] = *(const bf16x8*)(s2r + q * 64 + lq * 8);
      bq[sub][1] = *(const bf16x8*)(s2r + q * 64 + 32 + lq * 8);
    }
    // ---- phase 1: all score MFMAs (independent) ----
    f32x4 sacc[3][2];
#pragma unroll
    for (int mt = 0; mt < 3; mt++) {
      if (c * 32 + 31 <= pt[mt] * 16) continue;
#pragma unroll
      for (int sub = 0; sub < 2; sub++) {
        if (c * 32 + sub * 16 + 15 <= pt[mt] * 16) continue;
        f32x4 sv = (f32x4){0.f, 0.f, 0.f, 0.f};
        sv = MFMA_BF16(afr[mt][0], bq[sub][0], sv);
        sacc[mt][sub] = MFMA_BF16(afr[mt][1], bq[sub][1], sv);
      }
    }
    // ---- phase 2: all exps + LDS stores (per-mt buffers) ----
#pragma unroll
    for (int mt = 0; mt < 3; mt++) {
      if (c * 32 + 31 <= pt[mt] * 16) continue;
      bf16* mybuf = &wch[par][wave][mt][0];
#pragma unroll
      for (int sub = 0; sub < 2; sub++) {
        if (c * 32 + sub * 16 + 15 <= pt[mt] * 16) {
#pragma unroll
          for (int rg = 0; rg < 4; rg++) mybuf[(lq * 4 + rg) * 40 + sub * 16 + l16] = (bf16)0.f;
          continue;
        }
        int q = c * 32 + sub * 16 + l16;
        int p0 = pt[mt] * 16 + lq * 4;
#pragma unroll
        for (int rg = 0; rg < 4; rg++) {
          float wv = (q > p0 + rg) ? __expf(sacc[mt][sub][rg] * 0.015625f) : 0.f;
          lpart += wv;
          mybuf[(lq * 4 + rg) * 40 + sub * 16 + l16] = (bf16)wv;
        }
      }
    }
    // ---- phase 3: all ew MFMAs ----
#pragma unroll
    for (int mt = 0; mt < 3; mt++) {
      if (c * 32 + 31 <= pt[mt] * 16) continue;
      bf16x8 wf = *(const bf16x8*)(&wch[par][wave][mt][l16 * 40 + lq * 8]);
#pragma unroll
      for (int nt = 0; nt < 4; nt++) ewacc[mt][nt] = MFMA_BF16(wf, efr[nt], ewacc[mt][nt]);
    }
  }

  bf16* ewout = ew_bf + ((size_t)h * SEQ + r) * 12288;
#pragma unroll
  for (int mt = 0; mt < 3; mt++)
#pragma unroll
    for (int nt = 0; nt < 4; nt++)
#pragma unroll
      for (int rg = 0; rg < 4; rg++) {
        int p = pt[mt] * 16 + lq * 4 + rg;
        int g = nt * 16 + l16;
        ewout[p * 64 + g] = (bf16)(ewacc[mt][nt][rg] + ech[p * 64 + g]);
      }

#pragma unroll
  for (int off = 32; off > 0; off >>= 1) lpart += __shfl_down(lpart, off);
  if (lane == 0) redL[wave] = lpart;
  __syncthreads();
  if (tid == 0) Lsum[h * SEQ + r] = redL[0] + redL[1] + redL[2] + redL[3];
}

// =================== K5b: Zpart[ks][r][h*64+f] = ew'[h,32r,kslice] @ tTt[h,kslice] ===================
__global__ __launch_bounds__(512) void k5b_z(
    const bf16* __restrict__ ew_bf, const bf16* __restrict__ tTt, float* __restrict__ Zpart) {
  int h = blockIdx.x, mt = blockIdx.y, ks = blockIdx.z;
  int tid = threadIdx.x, wave = tid >> 6, lane = tid & 63;
  int lq = lane >> 4, l16 = lane & 15;
  __shared__ float zred[8][16][66];
  const bf16* ewh = ew_bf + ((size_t)h * SEQ + mt * 32) * 12288;
  const bf16* th = tTt + (size_t)h * 786432;
  f32x4 acc[2][4];
#pragma unroll
  for (int m2 = 0; m2 < 2; m2++)
#pragma unroll
    for (int nt = 0; nt < 4; nt++) acc[m2][nt] = (f32x4){0.f, 0.f, 0.f, 0.f};
  for (int jj = 0; jj < 6; jj++) {
    int kc = ks * 48 + wave * 6 + jj;  // 32-wide k chunk
    int p = kc >> 1, g0 = (kc & 1) * 32;
    bf16x8 af0 = *(const bf16x8*)(ewh + (size_t)l16 * 12288 + kc * 32 + lq * 8);
    bf16x8 af1 = *(const bf16x8*)(ewh + (size_t)(16 + l16) * 12288 + kc * 32 + lq * 8);
#pragma unroll
    for (int nt = 0; nt < 4; nt++) {
      bf16x8 tf = *(const bf16x8*)(th + (size_t)p * 4096 + (nt * 16 + l16) * 64 + g0 + lq * 8);
      acc[0][nt] = MFMA_BF16(af0, tf, acc[0][nt]);
      acc[1][nt] = MFMA_BF16(af1, tf, acc[1][nt]);
    }
  }
#pragma unroll
  for (int m2 = 0; m2 < 2; m2++) {
    if (m2) __syncthreads();
#pragma unroll
    for (int nt = 0; nt < 4; nt++)
#pragma unroll
      for (int rg = 0; rg < 4; rg++) zred[wave][lq * 4 + rg][nt * 16 + l16] = acc[m2][nt][rg];
    __syncthreads();
#pragma unroll
    for (int o = 0; o < 2; o++) {
      int idx = o * 512 + tid;  // 1024 outputs: [rloc 16][f 64]
      int rloc = idx >> 6, f = idx & 63;
      float s = 0.f;
#pragma unroll
      for (int wv = 0; wv < 8; wv++) s += zred[wv][rloc][f];
      Zpart[(size_t)ks * 98304 + (size_t)(mt * 32 + m2 * 16 + rloc) * 512 + h * 64 + f] = s;
    }
  }
}

// =================== K5c: z_bf[m][c] = (sum_ks Zpart) / L ===================
__global__ __launch_bounds__(256) void k5c_zf(const float* __restrict__ Zpart,
                                              const float* __restrict__ Lsum,
                                              bf16* __restrict__ z_bf) {
  int m = blockIdx.x, tid = threadIdx.x;
#pragma unroll
  for (int o = 0; o < 2; o++) {
    int c = o * 256 + tid;
    int h = c >> 6;
    float s = 0.f;
#pragma unroll
    for (int ks = 0; ks < 8; ks++) s += Zpart[(size_t)ks * 98304 + (size_t)m * 512 + c];
    float L = Lsum[h * SEQ + m] + 18528.0f;  // 18528 masked (p>=q) entries, weight exactly 1.0f
    z_bf[(size_t)m * 512 + c] = (bf16)(s / L);
  }
}

// =================== K6: out = z @ Wout^T + b_out (16m x 64n tiles, 4-way K-split) ===================
__global__ __launch_bounds__(256) void k6_out(
    const bf16* __restrict__ z_bf, const float* __restrict__ Wout,
    const float* __restrict__ b_out, float* __restrict__ out) {
  int bid = blockIdx.x, tid = threadIdx.x;
  int nb = bid & 7, mb = bid >> 3;  // 12 m-tiles of 16 rows
  int wave = tid >> 6, lane = tid & 63;
  int lq = lane >> 4, l16 = lane & 15;
  int m = mb * 16 + l16;
  f32x4 acc[4];
#pragma unroll
  for (int nt = 0; nt < 4; nt++) acc[nt] = (f32x4){0.f, 0.f, 0.f, 0.f};
#pragma unroll
  for (int kc = 0; kc < 4; kc++) {
    int k0 = wave * 128 + kc * 32;
    bf16x8 af = *(const bf16x8*)(z_bf + (size_t)m * 512 + k0 + lq * 8);
#pragma unroll
    for (int nt = 0; nt < 4; nt++) {
      f32x8 wv = *(const f32x8*)(Wout + (size_t)(nb * 64 + nt * 16 + l16) * 512 + k0 + lq * 8);
      acc[nt] = MFMA_BF16(af, cvt8(wv), acc[nt]);
    }
  }
  __shared__ float red[4][16][68];
#pragma unroll
  for (int nt = 0; nt < 4; nt++)
#pragma unroll
    for (int rg = 0; rg < 4; rg++) red[wave][lq * 4 + rg][nt * 16 + l16] = acc[nt][rg];
  __syncthreads();
#pragma unroll
  for (int o = 0; o < 4; o++) {
    int idx = o * 256 + tid;  // 1024 outputs: [rloc 16][f 64]
    int rloc = idx >> 6, f = idx & 63;
    float s = red[0][rloc][f] + red[1][rloc][f] + red[2][rloc][f] + red[3][rloc][f];
    out[(size_t)(mb * 16 + rloc) * 512 + nb * 64 + f] = s + b_out[nb * 64 + f];
  }
}

// =================== workspace layout (f32 units) ===================
static const size_t OFF_PROJ = 0;         // f32 491520
static const size_t OFF_ECUM = 491520;    // f32 98304
static const size_t OFF_XN = 589824;      // bf16 -> 49152
static const size_t OFF_ZPART = 638976;   // f32 786432 (8 slices x 98304)
static const size_t OFF_LSUM = 1425408;   // f32 1536
static const size_t OFF_Z = 1427456;      // bf16 98304 -> 49152
static const size_t OFF_WVT = 2473984;    // bf16 -> 1048576
static const size_t OFF_A = 3522560;      // bf16 -> 49152
static const size_t OFF_C = 3571712;      // 49152
static const size_t OFF_D = 3620864;      // 49152
static const size_t OFF_ET = 3670016;     // 49152
static const size_t OFF_BSUM = 3719168;   // 6144
static const size_t OFF_S1 = 3725312;     // bf16 -> 393216
static const size_t OFF_S2 = 4118528;     // bf16 -> 1179648
static const size_t OFF_TT = 5298176;     // bf16 -> 3145728
static const size_t OFF_EW = 8493056;     // bf16 -> 9437184
// TOTAL = 17930240 f32 = 71.7 MB

extern "C" void kernel_launch(void* const* d_in, const int* in_sizes, int n_in,
                              void* d_out, int out_size, void* d_ws, size_t ws_size,
                              hipStream_t stream) {
  (void)in_sizes; (void)n_in; (void)out_size; (void)ws_size;
  const float* x = (const float*)d_in[0];
  const float* ln_w = (const float*)d_in[1];
  const float* ln_b = (const float*)d_in[2];
  const float* W_abcde = (const float*)d_in[3];
  const float* b_abcde = (const float*)d_in[4];
  const float* W_K = (const float*)d_in[5];
  const float* W_V = (const float*)d_in[6];
  const float* W_out = (const float*)d_in[7];
  const float* b_out = (const float*)d_in[8];
  float* out = (float*)d_out;
  float* ws = (float*)d_ws;

  float* proj = ws + OFF_PROJ;
  float* ecum = ws + OFF_ECUM;
  bf16* xn_bf = (bf16*)(ws + OFF_XN);
  float* Zpart = ws + OFF_ZPART;
  float* Lsum = ws + OFF_LSUM;
  bf16* z_bf = (bf16*)(ws + OFF_Z);
  bf16* WVt2 = (bf16*)(ws + OFF_WVT);
  bf16* a_bf = (bf16*)(ws + OFF_A);
  bf16* c_bf = (bf16*)(ws + OFF_C);
  bf16* d_bf = (bf16*)(ws + OFF_D);
  bf16* eT_bf = (bf16*)(ws + OFF_ET);
  bf16* bsum_bf = (bf16*)(ws + OFF_BSUM);
  bf16* s1bf = (bf16*)(ws + OFF_S1);
  bf16* s2bf = (bf16*)(ws + OFF_S2);
  bf16* tTt = (bf16*)(ws + OFF_TT);
  bf16* ew_bf = (bf16*)(ws + OFF_EW);

  k1_prep<<<704, 256, 0, stream>>>(x, ln_w, ln_b, W_V, xn_bf, WVt2);
  k2_proj<<<120, 256, 0, stream>>>(xn_bf, W_abcde, b_abcde, proj, a_bf, c_bf, d_bf);
  k3_mid<<<1739, 256, 0, stream>>>(c_bf, W_K, s1bf, d_bf, WVt2, tTt, proj, eT_bf, ecum,
                                   bsum_bf);
  k4_step2<<<576, 256, 0, stream>>>(s1bf, bsum_bf, s2bf);
  k5_attn<<<dim3(SEQ, 8), 256, 0, stream>>>(a_bf, s2bf, eT_bf, ecum, ew_bf, Lsum);
  k5b_z<<<dim3(8, 6, 8), 512, 0, stream>>>(ew_bf, tTt, Zpart);
  k5c_zf<<<SEQ, 256, 0, stream>>>(Zpart, Lsum, z_bf);
  k6_out<<<96, 256, 0, stream>>>(z_bf, W_out, b_out, out);
}